// Round 11
// baseline (49.012 us; speedup 1.0000x reference)
//
#include <hip/hip_runtime.h>
#include <stdint.h>

#define DIM    1024
#define NEXP   20
#define NFRQ   3000
#define TOPK   5
#define BATCH  64

#define CHUNKS       128                    // chunks per row
#define CHUNK_ELEMS  (DIM * DIM / CHUNKS)   // 8192 elems (2^13) = 32 KiB
#define CHUNK_WORDS  (CHUNK_ELEMS / 32)     // 256 words = 1 KiB LDS bitmap
#define BUCKET_CAP   64                     // avg 23.4, sigma 4.8 -> +8.4 sigma

// d_ws layout (int units)
#define WS_EXPERT_OFF 0       // [BATCH*TOPK] = 320
#define WS_COUNTS_OFF 512     // [NEXP*CHUNKS] = 2560
#define WS_BINNED_OFF 4096    // [NEXP*CHUNKS*BUCKET_CAP] = 640 KiB

typedef float    f32x4 __attribute__((ext_vector_type(4)));
typedef uint32_t u32x4 __attribute__((ext_vector_type(4)));

// --- Kernel 1: router+top5 (blocks 0..63), index binning (blocks 64..83) ----
// Router: thread t -> expert e=t&31 (e<20), slice r=t>>5. LDS reduce, then
// wave-parallel top-5 via shfl_xor argmax (strict >, smaller-index tie-break
// == jax.lax.top_k; softmax monotonic -> top-k on logits == top-k on probs).
// Binning: bucket 3000 indices by idx>>13 into global lists; bucket ORDER is
// atomic-nondeterministic but the SET is deterministic; consumer only ORs
// bits -> output deterministic.
__global__ __launch_bounds__(512)
void front_kernel(const float* __restrict__ cls, const float* __restrict__ W,
                  const float* __restrict__ bias,
                  const int* __restrict__ list_indices, int* __restrict__ ws) {
    const int t = threadIdx.x;   // 0..511
    __shared__ float red[512];
    __shared__ int lcount[CHUNKS];

    if (blockIdx.x < BATCH) {
        const int row = blockIdx.x;
        const int e = t & 31;
        const int r = t >> 5;    // 0..15
        const float* x = cls + (size_t)row * DIM;
        float acc = 0.0f;
        if (e < NEXP) {
            #pragma unroll 8
            for (int i = 0; i < DIM / 16; ++i) {       // 64 MACs
                const int d = r * (DIM / 16) + i;
                acc += x[d] * W[(size_t)d * NEXP + e];
            }
        }
        red[t] = acc;
        __syncthreads();

        if (t < 64) {            // wave 0 only
            float v = -INFINITY;
            int   idx = t;
            if (t < NEXP) {
                v = bias[t];
                #pragma unroll
                for (int rr = 0; rr < 16; ++rr) v += red[rr * 32 + t];
            }
            #pragma unroll
            for (int k = 0; k < TOPK; ++k) {
                float bv = v; int bi = idx;
                #pragma unroll
                for (int off = 32; off >= 1; off >>= 1) {
                    const float ov = __shfl_xor(bv, off);
                    const int   oi = __shfl_xor(bi, off);
                    if (ov > bv || (ov == bv && oi < bi)) { bv = ov; bi = oi; }
                }
                if (t == 0) ws[WS_EXPERT_OFF + row * TOPK + k] = bi;
                if (idx == bi) v = -INFINITY;          // remove winner
            }
        }
    } else {
        const int e = blockIdx.x - BATCH;              // 0..19
        for (int i = t; i < CHUNKS; i += 512) lcount[i] = 0;
        __syncthreads();

        const int* tbl    = list_indices + (size_t)e * NFRQ;
        int*       binned = ws + WS_BINNED_OFF;
        for (int f = t; f < NFRQ; f += 512) {          // coalesced, 6 iters
            const int idx    = tbl[f];
            const int bucket = idx >> 13;              // CHUNK_ELEMS = 2^13
            const int slot   = atomicAdd(&lcount[bucket], 1);
            if (slot < BUCKET_CAP)
                binned[(size_t)(e * CHUNKS + bucket) * BUCKET_CAP + slot] = idx;
        }
        __syncthreads();
        for (int i = t; i < CHUNKS; i += 512)
            ws[WS_COUNTS_OFF + e * CHUNKS + i] = min(lcount[i], BUCKET_CAP);
    }
}

// --- Kernel 2: expand, deep-pipelined ----------------------------------------
// 8192 blocks x 256 threads = FOUR generations at 8 blocks/CU (1 KiB LDS,
// tiny VGPR): per-block preambles overlap other blocks' streaming, emulating
// the fill kernel's steady-state pipeline. Expert ids / counts are
// wave-uniform L2-hit loads issued by every thread directly (no LDS staging
// barrier); single barrier between bitmap build and stream. Each output byte
// is written exactly once, plain coalesced float4.
__global__ __launch_bounds__(256)
void expand_kernel(const int* __restrict__ ws, f32x4* __restrict__ out) {
    const int t     = threadIdx.x;              // 0..255
    const int b     = blockIdx.x >> 7;          // 0..63
    const int chunk = blockIdx.x & (CHUNKS - 1);

    __shared__ uint32_t bm[CHUNK_WORDS];        // 1 KiB

    bm[t] = 0u;                                 // 256 words, one store

    // uniform expert/count/segment loads (overlap the zeroing store)
    const int* binned = ws + WS_BINNED_OFF;
    #pragma unroll
    for (int k = 0; k < TOPK; ++k) {
        const int e = ws[WS_EXPERT_OFF + b * TOPK + k];        // uniform
        const int n = ws[WS_COUNTS_OFF + e * CHUNKS + chunk];  // uniform
        const int* seg = binned + (size_t)(e * CHUNKS + chunk) * BUCKET_CAP;
        const int idx = (t < n) ? seg[t] : -1;                 // n <= 64
        __syncthreads();   // k==0: covers bm zeroing; others: order atomics
        if (idx >= 0) {
            const uint32_t rel = (uint32_t)idx & (CHUNK_ELEMS - 1);
            atomicOr(&bm[rel >> 5], 1u << (rel & 31));         // LDS atomic
        }
    }
    __syncthreads();

    f32x4* dst = out + (size_t)b * (DIM * DIM / 4)
                     + (size_t)chunk * (CHUNK_ELEMS / 4);
    const int      wb = t >> 3;                 // base bitmap word
    const uint32_t s  = ((uint32_t)t & 7u) * 4u;
    #pragma unroll
    for (int i = 0; i < CHUNK_ELEMS / 4 / 256; ++i) {   // 8 float4/thread
        const uint32_t wv = bm[wb + i * 32];            // 8-lane broadcast
        f32x4 v;
        v.x = ((wv >> (s + 0)) & 1u) ? 1.0f : 0.0f;
        v.y = ((wv >> (s + 1)) & 1u) ? 1.0f : 0.0f;
        v.z = ((wv >> (s + 2)) & 1u) ? 1.0f : 0.0f;
        v.w = ((wv >> (s + 3)) & 1u) ? 1.0f : 0.0f;
        dst[t + i * 256] = v;                           // plain store
    }
}

extern "C" void kernel_launch(void* const* d_in, const int* in_sizes, int n_in,
                              void* d_out, int out_size, void* d_ws, size_t ws_size,
                              hipStream_t stream) {
    const float* cls          = (const float*)d_in[0];  // [64,1024]
    const float* W            = (const float*)d_in[1];  // [1024,20]
    const float* bias         = (const float*)d_in[2];  // [20]
    const int*   list_indices = (const int*)d_in[3];    // [20,3000]

    int* ws = (int*)d_ws;

    // 1) router top-5 (64 blocks) + expert-table binning (20 blocks)
    front_kernel<<<dim3(BATCH + NEXP), dim3(512), 0, stream>>>(
        cls, W, bias, list_indices, ws);

    // 2) expand: 4-generation deep-pipelined stream
    expand_kernel<<<dim3(BATCH * CHUNKS), dim3(256), 0, stream>>>(
        ws, (f32x4*)d_out);
}

// Round 12
// 48.199 us; speedup vs baseline: 1.0169x; 1.0169x over previous
//
#include <hip/hip_runtime.h>
#include <stdint.h>

#define DIM    1024
#define NEXP   20
#define NFRQ   3000
#define TOPK   5
#define BATCH  64

#define CHUNKS       128                    // chunks per row
#define CHUNK_ELEMS  (DIM * DIM / CHUNKS)   // 8192 elems (2^13) = 32 KiB
#define CHUNK_WORDS  (CHUNK_ELEMS / 32)     // 256 words = 1 KiB LDS bitmap
#define BUCKET_CAP   64                     // avg 23.4/bucket, cap at +8 sigma
#define NGEN         4                      // chunks per persistent block
#define EXP_GRID     (BATCH * CHUNKS / NGEN) // 2048 blocks

// d_ws layout (int units)
#define WS_EXPERT_OFF 0       // [BATCH*TOPK] = 320
#define WS_BINNED_OFF 512     // [NEXP*CHUNKS*BUCKET_CAP] = 640 KiB, -1-padded

typedef float    f32x4 __attribute__((ext_vector_type(4)));
typedef uint32_t u32x4 __attribute__((ext_vector_type(4)));

// Raw barrier: LDS-only ordering (lgkmcnt), NO vmcnt(0) drain — global
// prefetch loads and streaming stores stay in flight across phases.
// sched_barrier(0) fences compiler motion around the asm (guide rule #18).
#define RAW_BAR() do {                                          \
    asm volatile("s_waitcnt lgkmcnt(0)" ::: "memory");          \
    __builtin_amdgcn_sched_barrier(0);                          \
    __builtin_amdgcn_s_barrier();                               \
    __builtin_amdgcn_sched_barrier(0);                          \
} while (0)

// --- Kernel 1: router+top5 (blocks 0..63), index binning (blocks 64..83) ----
// Router: thread t -> expert e=t&31 (e<20), slice r=t>>5. LDS reduce, then
// wave-parallel top-5 via shfl_xor argmax (strict >, smaller-index tie-break
// == jax.lax.top_k; softmax monotonic -> top-k on logits == top-k on probs).
// Binning: init all my buckets to -1 (poisoned ws would alias valid indices),
// then bucket 3000 indices by idx>>13. Slot ORDER is atomic-nondeterministic
// but the SET is deterministic; consumer only ORs bits -> deterministic.
__global__ __launch_bounds__(512)
void front_kernel(const float* __restrict__ cls, const float* __restrict__ W,
                  const float* __restrict__ bias,
                  const int* __restrict__ list_indices, int* __restrict__ ws) {
    const int t = threadIdx.x;   // 0..511
    __shared__ float red[512];
    __shared__ int lcount[CHUNKS];

    if (blockIdx.x < BATCH) {
        const int row = blockIdx.x;
        const int e = t & 31;
        const int r = t >> 5;    // 0..15
        const float* x = cls + (size_t)row * DIM;
        float acc = 0.0f;
        if (e < NEXP) {
            #pragma unroll 8
            for (int i = 0; i < DIM / 16; ++i) {       // 64 MACs
                const int d = r * (DIM / 16) + i;
                acc += x[d] * W[(size_t)d * NEXP + e];
            }
        }
        red[t] = acc;
        __syncthreads();

        if (t < 64) {            // wave 0 only
            float v = -INFINITY;
            int   idx = t;
            if (t < NEXP) {
                v = bias[t];
                #pragma unroll
                for (int rr = 0; rr < 16; ++rr) v += red[rr * 32 + t];
            }
            #pragma unroll
            for (int k = 0; k < TOPK; ++k) {
                float bv = v; int bi = idx;
                #pragma unroll
                for (int off = 32; off >= 1; off >>= 1) {
                    const float ov = __shfl_xor(bv, off);
                    const int   oi = __shfl_xor(bi, off);
                    if (ov > bv || (ov == bv && oi < bi)) { bv = ov; bi = oi; }
                }
                if (t == 0) ws[WS_EXPERT_OFF + row * TOPK + k] = bi;
                if (idx == bi) v = -INFINITY;          // remove winner
            }
        }
    } else {
        const int e = blockIdx.x - BATCH;              // 0..19
        int* mybins = ws + WS_BINNED_OFF + (size_t)e * CHUNKS * BUCKET_CAP;

        // -1-pad all slots (every call; ws is not re-poisoned between replays
        // but this makes the result independent of prior ws contents)
        for (int i = t; i < CHUNKS * BUCKET_CAP; i += 512) mybins[i] = -1;
        for (int i = t; i < CHUNKS; i += 512) lcount[i] = 0;
        __syncthreads();   // pad stores + lcount visible before scatter

        const int* tbl = list_indices + (size_t)e * NFRQ;
        for (int f = t; f < NFRQ; f += 512) {          // coalesced, 6 iters
            const int idx    = tbl[f];
            const int bucket = idx >> 13;              // CHUNK_ELEMS = 2^13
            const int slot   = atomicAdd(&lcount[bucket], 1);
            if (slot < BUCKET_CAP)
                mybins[bucket * BUCKET_CAP + slot] = idx;
        }
    }
}

// --- Kernel 2: persistent software-pipelined expand --------------------------
// 2048 blocks x 256 thr (1 KiB LDS, <=64 VGPR -> 8 blocks/CU, 32 waves).
// Each block owns NGEN=4 CONSECUTIVE chunks of ONE row (gid = blockIdx*4+g;
// 4 | 128 so b = gid>>7 is block-constant): expert ids loaded once. Per gen:
// zero bitmap + issue NEXT gen's bucket loads (latency hides under current
// stream) -> raw barrier -> <=5 LDS atomicOr (t<64) -> raw barrier -> stream
// 32 KiB as plain coalesced float4 -> raw barrier. Raw barriers order LDS
// only (lgkmcnt); prefetch loads and streaming stores pipeline across all
// generation boundaries like the 7 TB/s fill kernel.
__global__ __launch_bounds__(256, 8)
void expand_kernel(const int* __restrict__ ws, f32x4* __restrict__ out) {
    const int t    = threadIdx.x;               // 0..255
    const int gid0 = blockIdx.x * NGEN;         // first chunk id
    const int b    = gid0 >> 7;                 // row, constant for all gens

    __shared__ uint32_t bm[CHUNK_WORDS];        // 1 KiB

    // prologue: expert ids (uniform) + gen-0 bucket slots
    int e[TOPK];
    #pragma unroll
    for (int k = 0; k < TOPK; ++k)
        e[k] = ws[WS_EXPERT_OFF + b * TOPK + k];

    const int* binned = ws + WS_BINNED_OFF;
    int idx[2][TOPK];
    #pragma unroll
    for (int k = 0; k < TOPK; ++k)
        idx[0][k] = (t < BUCKET_CAP)
            ? binned[(size_t)(e[k] * CHUNKS + (gid0 & (CHUNKS - 1))) * BUCKET_CAP + t]
            : -1;

    #pragma unroll
    for (int g = 0; g < NGEN; ++g) {            // fully unrolled: idx[g&1] static
        const int gid   = gid0 + g;
        const int chunk = gid & (CHUNKS - 1);

        bm[t] = 0u;                             // zero this gen's bitmap

        if (g + 1 < NGEN) {                     // prefetch next gen's buckets
            const int nchunk = (gid + 1) & (CHUNKS - 1);
            #pragma unroll
            for (int k = 0; k < TOPK; ++k)
                idx[(g + 1) & 1][k] = (t < BUCKET_CAP)
                    ? binned[(size_t)(e[k] * CHUNKS + nchunk) * BUCKET_CAP + t]
                    : -1;
        }

        RAW_BAR();                              // zero visible (lgkm only)

        if (t < BUCKET_CAP) {
            #pragma unroll
            for (int k = 0; k < TOPK; ++k) {
                const int v = idx[g & 1][k];    // vmcnt wait inserted here
                if (v >= 0) {
                    const uint32_t rel = (uint32_t)v & (CHUNK_ELEMS - 1);
                    atomicOr(&bm[rel >> 5], 1u << (rel & 31));
                }
            }
        }

        RAW_BAR();                              // atomics visible

        f32x4* dst = out + (size_t)b * (DIM * DIM / 4)
                         + (size_t)chunk * (CHUNK_ELEMS / 4);
        const int      wb = t >> 3;
        const uint32_t s  = ((uint32_t)t & 7u) * 4u;
        #pragma unroll
        for (int i = 0; i < CHUNK_ELEMS / 4 / 256; ++i) {   // 8 float4/thread
            const uint32_t wv = bm[wb + i * 32];            // 8-lane broadcast
            f32x4 v;
            v.x = ((wv >> (s + 0)) & 1u) ? 1.0f : 0.0f;
            v.y = ((wv >> (s + 1)) & 1u) ? 1.0f : 0.0f;
            v.z = ((wv >> (s + 2)) & 1u) ? 1.0f : 0.0f;
            v.w = ((wv >> (s + 3)) & 1u) ? 1.0f : 0.0f;
            dst[t + i * 256] = v;               // plain store, never drained
        }

        RAW_BAR();                              // ds_reads done -> bm reusable
    }
}

extern "C" void kernel_launch(void* const* d_in, const int* in_sizes, int n_in,
                              void* d_out, int out_size, void* d_ws, size_t ws_size,
                              hipStream_t stream) {
    const float* cls          = (const float*)d_in[0];  // [64,1024]
    const float* W            = (const float*)d_in[1];  // [1024,20]
    const float* bias         = (const float*)d_in[2];  // [20]
    const int*   list_indices = (const int*)d_in[3];    // [20,3000]

    int* ws = (int*)d_ws;

    // 1) router top-5 (64 blocks) + expert-table binning (20 blocks)
    front_kernel<<<dim3(BATCH + NEXP), dim3(512), 0, stream>>>(
        cls, W, bias, list_indices, ws);

    // 2) persistent pipelined expand: 2048 blocks x 4 chunks each
    expand_kernel<<<dim3(EXP_GRID), dim3(256), 0, stream>>>(
        ws, (f32x4*)d_out);
}

// Round 13
// 47.568 us; speedup vs baseline: 1.0304x; 1.0133x over previous
//
#include <hip/hip_runtime.h>
#include <stdint.h>

#define DIM    1024
#define NEXP   20
#define NFRQ   3000
#define TOPK   5
#define BATCH  64

#define CHUNKS       128                    // chunks per row
#define CHUNK_ELEMS  (DIM * DIM / CHUNKS)   // 8192 elems (2^13) = 32 KiB
#define CHUNK_WORDS  (CHUNK_ELEMS / 32)     // 256 words = 1 KiB LDS bitmap
#define BUCKET_CAP   64                     // avg 23.4/bucket, cap at +8 sigma
#define NGEN         4                      // chunks per persistent block
#define EXP_GRID     (BATCH * CHUNKS / NGEN) // 2048 blocks

// d_ws layout (int units)
#define WS_EXPERT_OFF 0       // [BATCH*TOPK] = 320
#define WS_BINNED_OFF 512     // [NEXP*CHUNKS*BUCKET_CAP] = 640 KiB, -1-padded

typedef float    f32x4 __attribute__((ext_vector_type(4)));
typedef uint32_t u32x4 __attribute__((ext_vector_type(4)));

// Raw barrier: LDS-only ordering (lgkmcnt), NO vmcnt(0) drain — global
// prefetch loads and streaming stores stay in flight across phases.
// sched_barrier(0) fences compiler motion around the asm (guide rule #18).
#define RAW_BAR() do {                                          \
    asm volatile("s_waitcnt lgkmcnt(0)" ::: "memory");          \
    __builtin_amdgcn_sched_barrier(0);                          \
    __builtin_amdgcn_s_barrier();                               \
    __builtin_amdgcn_sched_barrier(0);                          \
} while (0)

// --- Kernel 1: router+top5 (blocks 0..63), index binning (blocks 64..83) ----
// 1024 threads to halve the latency chains vs R12's 512:
// Router: thread t -> expert e=t&31 (e<20), slice r=t>>5 (32 slices x 32
// dims): 32 chained MACs (W-load latency chain halved, unroll-8 keeps 8 in
// flight). LDS reduce (32 partials), then wave-parallel top-5 via shfl_xor
// argmax (strict >, smaller-index tie-break == jax.lax.top_k; softmax
// monotonic -> top-k on logits == top-k on probs).
// Binning: -1-pad all buckets (8 stores/thread), then bucket 3000 indices by
// idx>>13 in 3 coalesced rounds. Slot ORDER is atomic-nondeterministic but
// the SET is deterministic; consumer only ORs bits -> deterministic.
__global__ __launch_bounds__(1024)
void front_kernel(const float* __restrict__ cls, const float* __restrict__ W,
                  const float* __restrict__ bias,
                  const int* __restrict__ list_indices, int* __restrict__ ws) {
    const int t = threadIdx.x;   // 0..1023
    __shared__ float red[1024];
    __shared__ int lcount[CHUNKS];

    if (blockIdx.x < BATCH) {
        const int row = blockIdx.x;
        const int e = t & 31;
        const int r = t >> 5;    // 0..31
        const float* x = cls + (size_t)row * DIM;
        float acc = 0.0f;
        if (e < NEXP) {
            #pragma unroll 8
            for (int i = 0; i < DIM / 32; ++i) {       // 32 MACs
                const int d = r * (DIM / 32) + i;
                acc += x[d] * W[(size_t)d * NEXP + e];
            }
        }
        red[t] = acc;
        __syncthreads();

        if (t < 64) {            // wave 0 only
            float v = -INFINITY;
            int   idx = t;
            if (t < NEXP) {
                v = bias[t];
                #pragma unroll
                for (int rr = 0; rr < 32; ++rr) v += red[rr * 32 + t];
            }
            #pragma unroll
            for (int k = 0; k < TOPK; ++k) {
                float bv = v; int bi = idx;
                #pragma unroll
                for (int off = 32; off >= 1; off >>= 1) {
                    const float ov = __shfl_xor(bv, off);
                    const int   oi = __shfl_xor(bi, off);
                    if (ov > bv || (ov == bv && oi < bi)) { bv = ov; bi = oi; }
                }
                if (t == 0) ws[WS_EXPERT_OFF + row * TOPK + k] = bi;
                if (idx == bi) v = -INFINITY;          // remove winner
            }
        }
    } else {
        const int e = blockIdx.x - BATCH;              // 0..19
        int* mybins = ws + WS_BINNED_OFF + (size_t)e * CHUNKS * BUCKET_CAP;

        // -1-pad all slots (result independent of prior ws contents)
        for (int i = t; i < CHUNKS * BUCKET_CAP; i += 1024) mybins[i] = -1;
        for (int i = t; i < CHUNKS; i += 1024) lcount[i] = 0;
        __syncthreads();   // pad stores + lcount visible before scatter

        const int* tbl = list_indices + (size_t)e * NFRQ;
        for (int f = t; f < NFRQ; f += 1024) {         // coalesced, 3 iters
            const int idx    = tbl[f];
            const int bucket = idx >> 13;              // CHUNK_ELEMS = 2^13
            const int slot   = atomicAdd(&lcount[bucket], 1);
            if (slot < BUCKET_CAP)
                mybins[bucket * BUCKET_CAP + slot] = idx;
        }
    }
}

// --- Kernel 2 (unchanged from R12): persistent software-pipelined expand ----
// 2048 blocks x 256 thr (1 KiB LDS -> 8 blocks/CU, 32 waves). Each block owns
// NGEN=4 consecutive chunks of one row; expert ids loaded once. Per gen: zero
// bitmap + prefetch next gen's buckets -> raw barrier -> <=5 LDS atomicOr
// (t<64) -> raw barrier -> stream 32 KiB plain coalesced float4 -> raw
// barrier. Raw barriers order LDS only; prefetch loads and streaming stores
// pipeline across generation boundaries.
__global__ __launch_bounds__(256, 8)
void expand_kernel(const int* __restrict__ ws, f32x4* __restrict__ out) {
    const int t    = threadIdx.x;               // 0..255
    const int gid0 = blockIdx.x * NGEN;         // first chunk id
    const int b    = gid0 >> 7;                 // row, constant for all gens

    __shared__ uint32_t bm[CHUNK_WORDS];        // 1 KiB

    // prologue: expert ids (uniform) + gen-0 bucket slots
    int e[TOPK];
    #pragma unroll
    for (int k = 0; k < TOPK; ++k)
        e[k] = ws[WS_EXPERT_OFF + b * TOPK + k];

    const int* binned = ws + WS_BINNED_OFF;
    int idx[2][TOPK];
    #pragma unroll
    for (int k = 0; k < TOPK; ++k)
        idx[0][k] = (t < BUCKET_CAP)
            ? binned[(size_t)(e[k] * CHUNKS + (gid0 & (CHUNKS - 1))) * BUCKET_CAP + t]
            : -1;

    #pragma unroll
    for (int g = 0; g < NGEN; ++g) {            // fully unrolled: idx[g&1] static
        const int gid   = gid0 + g;
        const int chunk = gid & (CHUNKS - 1);

        bm[t] = 0u;                             // zero this gen's bitmap

        if (g + 1 < NGEN) {                     // prefetch next gen's buckets
            const int nchunk = (gid + 1) & (CHUNKS - 1);
            #pragma unroll
            for (int k = 0; k < TOPK; ++k)
                idx[(g + 1) & 1][k] = (t < BUCKET_CAP)
                    ? binned[(size_t)(e[k] * CHUNKS + nchunk) * BUCKET_CAP + t]
                    : -1;
        }

        RAW_BAR();                              // zero visible (lgkm only)

        if (t < BUCKET_CAP) {
            #pragma unroll
            for (int k = 0; k < TOPK; ++k) {
                const int v = idx[g & 1][k];    // vmcnt wait inserted here
                if (v >= 0) {
                    const uint32_t rel = (uint32_t)v & (CHUNK_ELEMS - 1);
                    atomicOr(&bm[rel >> 5], 1u << (rel & 31));
                }
            }
        }

        RAW_BAR();                              // atomics visible

        f32x4* dst = out + (size_t)b * (DIM * DIM / 4)
                         + (size_t)chunk * (CHUNK_ELEMS / 4);
        const int      wb = t >> 3;
        const uint32_t s  = ((uint32_t)t & 7u) * 4u;
        #pragma unroll
        for (int i = 0; i < CHUNK_ELEMS / 4 / 256; ++i) {   // 8 float4/thread
            const uint32_t wv = bm[wb + i * 32];            // 8-lane broadcast
            f32x4 v;
            v.x = ((wv >> (s + 0)) & 1u) ? 1.0f : 0.0f;
            v.y = ((wv >> (s + 1)) & 1u) ? 1.0f : 0.0f;
            v.z = ((wv >> (s + 2)) & 1u) ? 1.0f : 0.0f;
            v.w = ((wv >> (s + 3)) & 1u) ? 1.0f : 0.0f;
            dst[t + i * 256] = v;               // plain store, never drained
        }

        RAW_BAR();                              // ds_reads done -> bm reusable
    }
}

extern "C" void kernel_launch(void* const* d_in, const int* in_sizes, int n_in,
                              void* d_out, int out_size, void* d_ws, size_t ws_size,
                              hipStream_t stream) {
    const float* cls          = (const float*)d_in[0];  // [64,1024]
    const float* W            = (const float*)d_in[1];  // [1024,20]
    const float* bias         = (const float*)d_in[2];  // [20]
    const int*   list_indices = (const int*)d_in[3];    // [20,3000]

    int* ws = (int*)d_ws;

    // 1) router top-5 (64 blocks) + expert-table binning (20 blocks)
    front_kernel<<<dim3(BATCH + NEXP), dim3(1024), 0, stream>>>(
        cls, W, bias, list_indices, ws);

    // 2) persistent pipelined expand: 2048 blocks x 4 chunks each
    expand_kernel<<<dim3(EXP_GRID), dim3(256), 0, stream>>>(
        ws, (f32x4*)d_out);
}